// Round 4
// baseline (418.924 us; speedup 1.0000x reference)
//
#include <hip/hip_runtime.h>

// LIF neuron scan: 16384 neurons x 2048 sequential steps.
// R4: producer/consumer wave specialization per block (128 thr = 2 waves,
// 64 neurons/block, 256 blocks = 1 block/CU).
//   producer wave: global_load_lds only (no VGPR dest, vmcnt = loads only,
//     hand-placed s_waitcnt vmcnt(48) -> 12 KB in flight/wave, 3 MB chip).
//   consumer wave: ds_read from 16-slot LDS ring + serial V/Vth chain +
//     regular (non-NT) spike stores (vmcnt = stores only, never waited).
// This decouples load latency from the serial chain and removes store-ack
// pollution of the load wait stream (R1-R3 plateau at ~2.5 TB/s).
//
// Exactness (binary spike output): contract(off), reference op order:
//   V = (V + 0.05f*(I-V)) + nz ; s = V>=Vth ; V = s?0:V ;
//   Vth = s ? min(max(Vth+0.1f,0.5f),2.0f) : Vth

constexpr int N  = 16384;   // neurons
constexpr int T  = 2048;    // sequential steps
constexpr int U  = 8;       // timesteps per chunk
constexpr int NC = T / U;   // 256 chunks
constexpr int R  = 16;      // LDS ring slots (64 KB)
constexpr int W  = 3;       // producer publish lag: wait vmcnt(16*W=48) <= 63

#define FLAG_LOAD(p)     __hip_atomic_load((p), __ATOMIC_RELAXED, __HIP_MEMORY_SCOPE_WORKGROUP)
#define FLAG_STORE(p, v) __hip_atomic_store((p), (v), __ATOMIC_RELAXED, __HIP_MEMORY_SCOPE_WORKGROUP)

__device__ __forceinline__ void gl_lds4(const float* g, float* l) {
    __builtin_amdgcn_global_load_lds(
        (const __attribute__((address_space(1))) void*)g,
        (__attribute__((address_space(3))) void*)l, 4, 0, 0);
}

__global__
__attribute__((amdgpu_flat_work_group_size(128, 128)))
void TorchLIFNeuronGroup_85152021610615_kernel(const float* __restrict__ I,
                                               const float* __restrict__ Z,
                                               float* __restrict__ O) {
    #pragma clang fp contract(off)
    __shared__ float ring[R][2][U][64];   // [slot][stream I/Z][u][neuron lane]
    __shared__ int ready_flag;            // highest chunk fully landed in LDS
    __shared__ int cons_flag;             // highest chunk consumed (slot free)

    if (threadIdx.x == 0) { ready_flag = -1; cons_flag = -1; }
    __syncthreads();

    if (threadIdx.x >= 64) {
        // ---------------- producer wave ----------------
        const int lane = threadIdx.x - 64;
        const float* gI = I + (size_t)blockIdx.x * 64 + lane;
        const float* gZ = Z + (size_t)blockIdx.x * 64 + lane;

        for (int k = 0; k < NC; ++k) {
            if (k >= R) {  // ring backpressure: slot k%R free iff consumed >= k-R
                while (FLAG_LOAD(&cons_flag) < k - R) __builtin_amdgcn_s_sleep(1);
            }
            __asm__ volatile("" ::: "memory");
            const int slot = k & (R - 1);
            const size_t tb = (size_t)k * U * N;
            #pragma unroll
            for (int u = 0; u < U; ++u) {
                gl_lds4(gI + tb + (size_t)u * N, &ring[slot][0][u][0]);
                gl_lds4(gZ + tb + (size_t)u * N, &ring[slot][1][u][0]);
            }
            if (k >= W) {
                // all but the newest 3 slots (48 ops) retired -> chunk k-W landed
                __asm__ volatile("s_waitcnt vmcnt(48)" ::: "memory");
                if (lane == 0) FLAG_STORE(&ready_flag, k - W);
            }
        }
        __asm__ volatile("s_waitcnt vmcnt(0)" ::: "memory");
        if (lane == 0) FLAG_STORE(&ready_flag, NC - 1);

    } else {
        // ---------------- consumer wave ----------------
        const int lane = threadIdx.x;
        float* op = O + (size_t)blockIdx.x * 64 + lane;

        float V   = 0.0f;   // V_RESET
        float Vth = 1.0f;   // V_TH0
        float ai[U], az[U], bi[U], bz[U];

        // prologue: chunk 0 -> a
        while (FLAG_LOAD(&ready_flag) < 0) __builtin_amdgcn_s_sleep(1);
        __asm__ volatile("" ::: "memory");
        #pragma unroll
        for (int u = 0; u < U; ++u) { ai[u] = ring[0][0][u][lane]; az[u] = ring[0][1][u][lane]; }

        for (int k = 0; k < NC; k += 2) {
            // prefetch chunk k+1 -> b (k+1 < NC always; NC even)
            while (FLAG_LOAD(&ready_flag) < k + 1) __builtin_amdgcn_s_sleep(1);
            __asm__ volatile("" ::: "memory");
            {
                const int slot = (k + 1) & (R - 1);
                #pragma unroll
                for (int u = 0; u < U; ++u) { bi[u] = ring[slot][0][u][lane]; bz[u] = ring[slot][1][u][lane]; }
            }
            // compute chunk k from a
            #pragma unroll
            for (int u = 0; u < U; ++u) {
                #pragma clang fp contract(off)
                float d  = ai[u] - V;
                float v1 = V + 0.05f * d;           // DT/TAU
                float v2 = v1 + az[u];
                bool  s  = (v2 >= Vth);
                V = s ? 0.0f : v2;
                float nth = fminf(fmaxf(Vth + 0.1f, 0.5f), 2.0f);
                Vth = s ? nth : Vth;
                op[(size_t)(k * U + u) * N] = s ? 1.0f : 0.0f;  // regular store
            }
            __asm__ volatile("" ::: "memory");
            if (lane == 0) FLAG_STORE(&cons_flag, k);

            // prefetch chunk k+2 -> a
            if (k + 2 < NC) {
                while (FLAG_LOAD(&ready_flag) < k + 2) __builtin_amdgcn_s_sleep(1);
                __asm__ volatile("" ::: "memory");
                const int slot = (k + 2) & (R - 1);
                #pragma unroll
                for (int u = 0; u < U; ++u) { ai[u] = ring[slot][0][u][lane]; az[u] = ring[slot][1][u][lane]; }
            }
            // compute chunk k+1 from b
            #pragma unroll
            for (int u = 0; u < U; ++u) {
                #pragma clang fp contract(off)
                float d  = bi[u] - V;
                float v1 = V + 0.05f * d;
                float v2 = v1 + bz[u];
                bool  s  = (v2 >= Vth);
                V = s ? 0.0f : v2;
                float nth = fminf(fmaxf(Vth + 0.1f, 0.5f), 2.0f);
                Vth = s ? nth : Vth;
                op[(size_t)((k + 1) * U + u) * N] = s ? 1.0f : 0.0f;
            }
            __asm__ volatile("" ::: "memory");
            if (lane == 0) FLAG_STORE(&cons_flag, k + 1);
        }
    }
}

extern "C" void kernel_launch(void* const* d_in, const int* in_sizes, int n_in,
                              void* d_out, int out_size, void* d_ws, size_t ws_size,
                              hipStream_t stream) {
    const float* input_current = (const float*)d_in[0];
    const float* noise         = (const float*)d_in[1];
    float* out                 = (float*)d_out;

    // 256 blocks x 128 threads: 64 neurons/block (consumer wave) + producer wave.
    TorchLIFNeuronGroup_85152021610615_kernel<<<N / 64, 128, 0, stream>>>(
        input_current, noise, out);
}

// Round 5
// 326.411 us; speedup vs baseline: 1.2834x; 1.2834x over previous
//
#include <hip/hip_runtime.h>

// LIF neuron scan: 16384 neurons x 2048 sequential steps (batch axis is a
// nonlinear per-neuron scan). 64 neurons per block, 256 blocks = 1 block/CU.
//
// R5: multi-producer wave specialization. Evidence R1-R4: a single wave's
// memory-level parallelism is stuck at ~14 outstanding loads regardless of
// source-level pipelining (2.5 TB/s ceiling); a lone producer wave also
// serializes (R4, 1.2 TB/s). Fix: 7 producer waves per block, each fully
// latency-TOLERANT (load chunk -> vmcnt(0) via reg use -> ds_write -> flag),
// throughput = 7 waves x 256 blocks concurrency >> Little's-law need.
// Consumer wave carries the serial V/Vth chain from an LDS ring; its vmcnt
// stream holds only output stores and is never waited. Handshakes use
// relaxed LDS atomics + explicit lgkmcnt(0) only (no vmcnt pollution).
//
// Exactness (binary spike output): contract(off), reference op order:
//   V = (V + 0.05f*(I-V)) + nz ; s = V>=Vth ; V = s?0:V ;
//   Vth = s ? min(max(Vth+0.1f,0.5f),2.0f) : Vth

constexpr int N  = 16384;   // neurons
constexpr int T  = 2048;    // sequential steps
constexpr int U  = 16;      // timesteps per chunk
constexpr int NC = T / U;   // 128 chunks
constexpr int S  = 12;      // LDS ring slots (12 x 8KB = 96KB)
constexpr int NP = 7;       // producer waves

__global__
__attribute__((amdgpu_flat_work_group_size(512, 512)))
void TorchLIFNeuronGroup_85152021610615_kernel(const float* __restrict__ I,
                                               const float* __restrict__ Z,
                                               float* __restrict__ O) {
    #pragma clang fp contract(off)
    __shared__ float ring[S][2][U][64];   // [slot][stream I/Z][u][lane] = 96KB
    __shared__ int   flags[NC];           // chunk k landed in LDS
    __shared__ int   cons;                // highest chunk consumed (slot free)

    // init handshake state
    if (threadIdx.x < NC) flags[threadIdx.x] = 0;
    if (threadIdx.x == 0) cons = -1;
    __syncthreads();

    const int wave = threadIdx.x >> 6;
    const int lane = threadIdx.x & 63;
    const int nb   = blockIdx.x * 64 + lane;   // this lane's neuron

    if (wave >= 1) {
        // ---------------- producer waves (1..7) ----------------
        const int p = wave - 1;
        const float* gI = I + nb;
        const float* gZ = Z + nb;

        for (int k = p; k < NC; k += NP) {
            // backpressure: slot k%S reusable once chunk k-S consumed
            while (__hip_atomic_load(&cons, __ATOMIC_RELAXED,
                                     __HIP_MEMORY_SCOPE_WORKGROUP) < k - S)
                __builtin_amdgcn_s_sleep(1);
            __asm__ volatile("" ::: "memory");

            const int    slot = k % S;
            const size_t t0   = (size_t)k * U;
            float vi[U], vz[U];
            #pragma unroll
            for (int u = 0; u < U; ++u) {
                vi[u] = gI[(t0 + u) * N];
                vz[u] = gZ[(t0 + u) * N];
            }
            #pragma unroll
            for (int u = 0; u < U; ++u) {
                ring[slot][0][u][lane] = vi[u];   // lane-stride-1: conflict-free
                ring[slot][1][u][lane] = vz[u];
            }
            // publish: data writes retired (lgkm only -- no vmcnt drain)
            __asm__ volatile("s_waitcnt lgkmcnt(0)" ::: "memory");
            if (lane == 0)
                __hip_atomic_store(&flags[k], 1, __ATOMIC_RELAXED,
                                   __HIP_MEMORY_SCOPE_WORKGROUP);
        }

    } else {
        // ---------------- consumer wave (0) ----------------
        float* op = O + nb;
        float V   = 0.0f;   // V_RESET
        float Vth = 1.0f;   // V_TH0
        float ai[U], az[U], bi[U], bz[U];

        // prologue: chunk 0 -> a
        while (__hip_atomic_load(&flags[0], __ATOMIC_ACQUIRE,
                                 __HIP_MEMORY_SCOPE_WORKGROUP) == 0)
            __builtin_amdgcn_s_sleep(1);
        #pragma unroll
        for (int u = 0; u < U; ++u) { ai[u] = ring[0][0][u][lane]; az[u] = ring[0][1][u][lane]; }

        for (int k = 0; k < NC; k += 2) {
            // prefetch chunk k+1 -> b (NC even, so k+1 < NC)
            while (__hip_atomic_load(&flags[k + 1], __ATOMIC_ACQUIRE,
                                     __HIP_MEMORY_SCOPE_WORKGROUP) == 0)
                __builtin_amdgcn_s_sleep(1);
            {
                const int slot = (k + 1) % S;
                #pragma unroll
                for (int u = 0; u < U; ++u) { bi[u] = ring[slot][0][u][lane]; bz[u] = ring[slot][1][u][lane]; }
            }
            // compute chunk k from a; stores go to the (never-waited) vm stream
            #pragma unroll
            for (int u = 0; u < U; ++u) {
                #pragma clang fp contract(off)
                float d  = ai[u] - V;
                float v1 = V + 0.05f * d;           // DT/TAU
                float v2 = v1 + az[u];
                bool  s  = (v2 >= Vth);
                V = s ? 0.0f : v2;
                float nth = fminf(fmaxf(Vth + 0.1f, 0.5f), 2.0f);
                Vth = s ? nth : Vth;
                op[(size_t)(k * U + u) * N] = s ? 1.0f : 0.0f;
            }
            // free chunk k's slot (a-regs were read; lgkm only)
            __asm__ volatile("s_waitcnt lgkmcnt(0)" ::: "memory");
            if (lane == 0)
                __hip_atomic_store(&cons, k, __ATOMIC_RELAXED,
                                   __HIP_MEMORY_SCOPE_WORKGROUP);

            // prefetch chunk k+2 -> a
            if (k + 2 < NC) {
                while (__hip_atomic_load(&flags[k + 2], __ATOMIC_ACQUIRE,
                                         __HIP_MEMORY_SCOPE_WORKGROUP) == 0)
                    __builtin_amdgcn_s_sleep(1);
                const int slot = (k + 2) % S;
                #pragma unroll
                for (int u = 0; u < U; ++u) { ai[u] = ring[slot][0][u][lane]; az[u] = ring[slot][1][u][lane]; }
            }
            // compute chunk k+1 from b
            #pragma unroll
            for (int u = 0; u < U; ++u) {
                #pragma clang fp contract(off)
                float d  = bi[u] - V;
                float v1 = V + 0.05f * d;
                float v2 = v1 + bz[u];
                bool  s  = (v2 >= Vth);
                V = s ? 0.0f : v2;
                float nth = fminf(fmaxf(Vth + 0.1f, 0.5f), 2.0f);
                Vth = s ? nth : Vth;
                op[(size_t)((k + 1) * U + u) * N] = s ? 1.0f : 0.0f;
            }
            __asm__ volatile("s_waitcnt lgkmcnt(0)" ::: "memory");
            if (lane == 0)
                __hip_atomic_store(&cons, k + 1, __ATOMIC_RELAXED,
                                   __HIP_MEMORY_SCOPE_WORKGROUP);
        }
    }
}

extern "C" void kernel_launch(void* const* d_in, const int* in_sizes, int n_in,
                              void* d_out, int out_size, void* d_ws, size_t ws_size,
                              hipStream_t stream) {
    const float* input_current = (const float*)d_in[0];
    const float* noise         = (const float*)d_in[1];
    float* out                 = (float*)d_out;

    // 256 blocks x 512 threads: 1 consumer + 7 producer waves, 64 neurons/block.
    TorchLIFNeuronGroup_85152021610615_kernel<<<N / 64, 512, 0, stream>>>(
        input_current, noise, out);
}